// Round 5
// baseline (1505.261 us; speedup 1.0000x reference)
//
#include <hip/hip_runtime.h>
#include <hip/hip_fp16.h>

#define D_DIM 1024
#define E_NUM 4
#define F_DIM 4096
#define NTOK 8192         // B*S = 4*2048
#define MT 64             // tokens per tile
#define FC 256            // F-chunk width (slow kernel)
#define FC2 128           // F-chunk width (fast kernel, LDS-budget forced)
#define KC 256            // K-chunk for X staging (slow kernel)
#define FHALF 2048        // F per block (F split in 2)
#define NWORK 520         // 8 XCDs * 65 work slots (>= 2 * max total tiles = 520)

typedef _Float16 half8_t __attribute__((ext_vector_type(8)));
typedef _Float16 half4_t __attribute__((ext_vector_type(4)));
typedef float floatx4 __attribute__((ext_vector_type(4)));

// ---------------- gating: top-2 selection, block-aggregated routing lists ------
// 32 tokens per 256-thread block. Only 4 atomicAdds per block -> 1024 total.
// Fuses x fp32->fp16 conversion.
template<bool WRITE_XH>
__global__ __launch_bounds__(256) void gate_kernel(
    const float* __restrict__ x, const float* __restrict__ Wg,
    const float* __restrict__ bg, _Float16* __restrict__ xh,
    int* __restrict__ cnt, int* __restrict__ lists)
{
    __shared__ int sel[32];
    __shared__ int loc[4][32];
    __shared__ int lbase[4], lnum[4];

    int wave = threadIdx.x >> 6;
    int lane = threadIdx.x & 63;
    int tbase = blockIdx.x * 32;

    for (int i = 0; i < 8; ++i) {
        int slot = wave * 8 + i;
        int tok = tbase + slot;
        const float* xr = x + (size_t)tok * D_DIM;
        double a0 = 0.0, a1 = 0.0, a2 = 0.0, a3 = 0.0;
        #pragma unroll
        for (int it = 0; it < 4; ++it) {
            int i0 = it * 256 + lane * 4;
            float4 xv = *(const float4*)(xr + i0);
            if (WRITE_XH) {
                half4_t hv = { (_Float16)xv.x, (_Float16)xv.y,
                               (_Float16)xv.z, (_Float16)xv.w };
                *(half4_t*)(xh + (size_t)tok * D_DIM + i0) = hv;
            }
            float4 w0 = *(const float4*)(Wg + (size_t)i0 * 4);
            float4 w1 = *(const float4*)(Wg + (size_t)i0 * 4 + 4);
            float4 w2 = *(const float4*)(Wg + (size_t)i0 * 4 + 8);
            float4 w3 = *(const float4*)(Wg + (size_t)i0 * 4 + 12);
            a0 += (double)xv.x * w0.x + (double)xv.y * w1.x
                + (double)xv.z * w2.x + (double)xv.w * w3.x;
            a1 += (double)xv.x * w0.y + (double)xv.y * w1.y
                + (double)xv.z * w2.y + (double)xv.w * w3.y;
            a2 += (double)xv.x * w0.z + (double)xv.y * w1.z
                + (double)xv.z * w2.z + (double)xv.w * w3.z;
            a3 += (double)xv.x * w0.w + (double)xv.y * w1.w
                + (double)xv.z * w2.w + (double)xv.w * w3.w;
        }
        #pragma unroll
        for (int off = 32; off > 0; off >>= 1) {
            a0 += __shfl_down(a0, off);
            a1 += __shfl_down(a1, off);
            a2 += __shfl_down(a2, off);
            a3 += __shfl_down(a3, off);
        }
        if (lane == 0) {
            double lg[4] = { a0 + (double)bg[0], a1 + (double)bg[1],
                             a2 + (double)bg[2], a3 + (double)bg[3] };
            int i1 = 0;
            for (int e = 1; e < 4; ++e) if (lg[e] > lg[i1]) i1 = e;   // first max wins
            int i2 = -1;
            for (int e = 0; e < 4; ++e) {
                if (e == i1) continue;
                if (i2 < 0 || lg[e] > lg[i2]) i2 = e;
            }
            sel[slot] = i1 * 4 + i2;
        }
    }
    __syncthreads();
    if (threadIdx.x < 4) {
        int e = threadIdx.x, n = 0;
        for (int s = 0; s < 32; ++s) {
            int v = sel[s];
            if ((v >> 2) == e || (v & 3) == e) loc[e][n++] = tbase + s;
        }
        lnum[e] = n;
        lbase[e] = atomicAdd(&cnt[e], n);
    }
    __syncthreads();
    {
        int e = threadIdx.x >> 6;
        int j = threadIdx.x & 63;
        if (j < lnum[e]) lists[e * NTOK + lbase[e] + j] = loc[e][j];
    }
}

// ---------------- prep: pack fp32 [z][R(k)][C(n)] into MFMA fragment tiles ----------
// Fragment (nb, kb) = 16 n-cols x 32 k-rows, 512 halves, stored so that
// half8 index (quad*16+ln) == lane: dst[frag*512 + quad*128 + ln*8 + j]
//   = src[kb*32 + quad*8 + j][nb*16 + ln]
__global__ __launch_bounds__(256) void tile_pack_kernel(
    const float* __restrict__ src, _Float16* __restrict__ dst, int R, int C)
{
    __shared__ _Float16 t2[32][36];     // [c_local][r_local]
    int r0 = blockIdx.y * 32, c0 = blockIdx.x * 32;
    const float* s = src + (size_t)blockIdx.z * R * C;
    _Float16* d = dst + (size_t)blockIdx.z * R * C;
    int tx = threadIdx.x & 31, ty = threadIdx.x >> 5;
    #pragma unroll
    for (int i = 0; i < 4; ++i) {
        int r = ty + i * 8;
        t2[tx][r] = (_Float16)s[(size_t)(r0 + r) * C + c0 + tx];
    }
    __syncthreads();
    int KB = R >> 5;
    int idx = threadIdx.x * 4;                 // 4 halves per thread
    int frag_h = idx >> 9;
    int rem = idx & 511;
    int quad = rem >> 7, ln = (rem >> 3) & 15, j0 = rem & 7;
    int cl = frag_h * 16 + ln, rl = quad * 8 + j0;
    half4_t v = { t2[cl][rl], t2[cl][rl + 1], t2[cl][rl + 2], t2[cl][rl + 3] };
    size_t off = ((size_t)(((c0 >> 4) + frag_h) * KB + (r0 >> 5))) * 512 + rem;
    *(half4_t*)&d[off] = v;
}

// ---------------- fast fused MLP: single-stage full-D X tile ----------------
// X[64][1024] staged into LDS ONCE per block (padded +8 -> 2-way-free reads),
// then 16 fc chunks of pure compute with only 2 barriers each:
//   GEMM1 (K=1024 straight from LDS) | barrier | swish->Hs | barrier | GEMM2
// vs the old 8x re-staging (80 barriers, exposed load latency per kc).
// XCD-aware decode kept: work = (b&7)*65 + (b>>3), works ordered
// (fhalf-major, expert-major, tile-minor) -> weight stream shared via L2.
__global__ __launch_bounds__(512, 2) void moe_fast_kernel(
    const _Float16* __restrict__ xh, const _Float16* __restrict__ W1m,
    const float* __restrict__ b1, const _Float16* __restrict__ W2m,
    const float* __restrict__ b2, const int* __restrict__ cnt,
    const int* __restrict__ lists, float* __restrict__ out)
{
    __shared__ _Float16 Xs[MT][D_DIM + 8];   // 129 KB, +8 pad: 4-bank row rotation
    __shared__ _Float16 Hs[MT][FC2 + 8];     // 17 KB
    __shared__ int tks[MT];

    // ---- XCD-aware work decode (fhalf-major, expert-major, tile-minor) ----
    int b = blockIdx.x;
    int work = (b & 7) * (NWORK / 8) + (b >> 3);

    int nb0 = (cnt[0] + MT - 1) / MT;
    int nb1 = (cnt[1] + MT - 1) / MT;
    int nb2 = (cnt[2] + MT - 1) / MT;
    int nb3 = (cnt[3] + MT - 1) / MT;
    int T = nb0 + nb1 + nb2 + nb3;          // total tiles (<=260)

    int fhalf, r;
    if (work < T) { fhalf = 0; r = work; }
    else if (work < 2 * T) { fhalf = 1; r = work - T; }
    else return;

    int expert, tile, mcnt;
    if (r < nb0)                  { expert = 0; tile = r; }
    else if (r < nb0 + nb1)       { expert = 1; tile = r - nb0; }
    else if (r < nb0 + nb1 + nb2) { expert = 2; tile = r - nb0 - nb1; }
    else                          { expert = 3; tile = r - nb0 - nb1 - nb2; }
    mcnt = min(MT, cnt[expert] - tile * MT);

    if (threadIdx.x < MT) {
        int idx = tile * MT + (int)threadIdx.x;
        tks[threadIdx.x] = lists[expert * NTOK + ((int)threadIdx.x < mcnt ? idx : tile * MT)];
    }
    __syncthreads();

    // fragment-tiled weight views (half8 units; frag stride = 64 half8s)
    const half8_t* W1f = (const half8_t*)(W1m + (size_t)expert * D_DIM * F_DIM);
    const half8_t* W2f = (const half8_t*)(W2m + (size_t)expert * D_DIM * F_DIM);
    const float* b1e = b1 + (size_t)expert * F_DIM;
    const float* b2e = b2 + (size_t)expert * D_DIM;

    int w = threadIdx.x >> 6;        // wave 0..7
    int lane = threadIdx.x & 63;
    int quad = lane >> 4;
    int ln = lane & 15;

    int srow = threadIdx.x >> 3;     // staging row 0..63
    int stg  = threadIdx.x & 7;      // 8 threads/row

    // ---- stage full X rows once: 4 chunks x 32 halves per thread ----
    {
        const _Float16* xr = xh + (size_t)tks[srow] * D_DIM + stg * 32;
        #pragma unroll
        for (int c = 0; c < 4; ++c) {
            half8_t v0 = *(const half8_t*)(xr + c * 256);
            half8_t v1 = *(const half8_t*)(xr + c * 256 + 8);
            half8_t v2 = *(const half8_t*)(xr + c * 256 + 16);
            half8_t v3 = *(const half8_t*)(xr + c * 256 + 24);
            int cbase = c * 256 + stg * 32;
            *(half8_t*)&Xs[srow][cbase]      = v0;
            *(half8_t*)&Xs[srow][cbase + 8]  = v1;
            *(half8_t*)&Xs[srow][cbase + 16] = v2;
            *(half8_t*)&Xs[srow][cbase + 24] = v3;
        }
    }
    __syncthreads();

    floatx4 oacc[4][8];
    #pragma unroll
    for (int mt = 0; mt < 4; ++mt)
        #pragma unroll
        for (int nt = 0; nt < 8; ++nt)
            oacc[mt][nt] = (floatx4){0.f, 0.f, 0.f, 0.f};

    int fbase = fhalf * FHALF;

    for (int fc = 0; fc < FHALF / FC2; ++fc) {   // 16 chunks of 128 f-cols
        int f0 = fbase + fc * FC2;
        int fb = (f0 >> 4) + w;                  // wave covers 16 f-cols at f0+w*16
        const half8_t* w1p = W1f + (size_t)fb * 32 * 64 + lane;   // frag (fb, kb)

        floatx4 hacc[4];
        hacc[0] = hacc[1] = hacc[2] = hacc[3] = (floatx4){0.f, 0.f, 0.f, 0.f};

        // GEMM1: H[64 x 16] += X[64 x 1024] @ W1[1024 x 16], all from LDS
        #pragma unroll
        for (int ks = 0; ks < 32; ++ks) {
            half8_t bfr = w1p[(size_t)ks * 64];
            int kk = ks * 32 + quad * 8;
            #pragma unroll
            for (int mt = 0; mt < 4; ++mt) {
                half8_t a = *(const half8_t*)&Xs[mt * 16 + ln][kk];
                hacc[mt] = __builtin_amdgcn_mfma_f32_16x16x32_f16(
                    a, bfr, hacc[mt], 0, 0, 0);
            }
        }
        __syncthreads();   // prior GEMM2 reads of Hs done before we overwrite

        // bias + swish, H -> LDS (fp16); wave owns cols w*16..w*16+15
        {
            float b1v = b1e[f0 + w * 16 + ln];
            #pragma unroll
            for (int mt = 0; mt < 4; ++mt)
                #pragma unroll
                for (int r2 = 0; r2 < 4; ++r2) {
                    float v = hacc[mt][r2] + b1v;
                    float hs = v / (1.f + __expf(-v));
                    Hs[mt * 16 + quad * 4 + r2][w * 16 + ln] = (_Float16)hs;
                }
        }
        __syncthreads();

        // GEMM2: Out += H @ W2[f-range, :]
        #pragma unroll
        for (int ks = 0; ks < FC2 / 32; ++ks) {  // 4
            int kk = ks * 32 + quad * 8;
            int fkb = (f0 >> 5) + ks;            // k-frag index in f-dim
            half8_t a[4];
            #pragma unroll
            for (int mt = 0; mt < 4; ++mt)
                a[mt] = *(const half8_t*)&Hs[mt * 16 + ln][kk];
            #pragma unroll
            for (int nt = 0; nt < 8; ++nt) {
                int db = w * 8 + nt;             // d-frag index (16-wide)
                half8_t bfr = W2f[((size_t)(db * 128 + fkb)) * 64 + lane];
                #pragma unroll
                for (int mt = 0; mt < 4; ++mt)
                    oacc[mt][nt] = __builtin_amdgcn_mfma_f32_16x16x32_f16(
                        a[mt], bfr, oacc[mt][nt], 0, 0, 0);
            }
        }
        // no barrier: next GEMM1 touches only Xs; post-GEMM1 barrier orders
        // these Hs reads vs the next swish writes
    }

    // epilogue: scatter-add (each token has exactly 2 expert contributions)
    #pragma unroll
    for (int mt = 0; mt < 4; ++mt) {
        #pragma unroll
        for (int r2 = 0; r2 < 4; ++r2) {
            int row = mt * 16 + quad * 4 + r2;
            if (row >= mcnt) continue;
            float* orow = out + (size_t)tks[row] * D_DIM;
            #pragma unroll
            for (int nt = 0; nt < 8; ++nt) {
                int dcol = w * 128 + nt * 16 + ln;
                float v = oacc[mt][nt][r2];
                if (fhalf == 0) v += b2e[dcol];   // bias exactly once per (tok,expert)
                atomicAdd(orow + dcol, v);
            }
        }
    }
}

// ---------------- fallback kernel: fp32 weights on the fly (ws too small) ----------
__global__ __launch_bounds__(512, 2) void moe_slow_kernel(
    const float* __restrict__ x, const float* __restrict__ W1,
    const float* __restrict__ b1, const float* __restrict__ W2,
    const float* __restrict__ b2, const int* __restrict__ cnt,
    const int* __restrict__ lists, float* __restrict__ out)
{
    __shared__ _Float16 Xs[MT][KC + 8];
    __shared__ _Float16 Hs[MT][FC + 8];
    __shared__ int tks[MT];

    int fhalf = blockIdx.x & 1;
    int bi = blockIdx.x >> 1;
    int expert = -1, tile = 0, mcnt = 0;
    int rem = bi;
    for (int e = 0; e < E_NUM; ++e) {
        int n = cnt[e];
        int nbt = (n + MT - 1) / MT;
        if (rem < nbt) { expert = e; tile = rem; mcnt = min(MT, n - rem * MT); break; }
        rem -= nbt;
    }
    if (expert < 0) return;

    if (threadIdx.x < MT) {
        int idx = tile * MT + (int)threadIdx.x;
        tks[threadIdx.x] = lists[expert * NTOK + ((int)threadIdx.x < mcnt ? idx : tile * MT)];
    }
    __syncthreads();

    const float* W1e = W1 + (size_t)expert * D_DIM * F_DIM;
    const float* W2e = W2 + (size_t)expert * F_DIM * D_DIM;
    const float* b1e = b1 + (size_t)expert * F_DIM;
    const float* b2e = b2 + (size_t)expert * D_DIM;

    int w = threadIdx.x >> 6;
    int lane = threadIdx.x & 63;
    int quad = lane >> 4;
    int ln = lane & 15;

    floatx4 oacc[4][8];
    #pragma unroll
    for (int mt = 0; mt < 4; ++mt)
        #pragma unroll
        for (int nt = 0; nt < 8; ++nt)
            oacc[mt][nt] = (floatx4){0.f, 0.f, 0.f, 0.f};

    int fbase = fhalf * FHALF;
    int srow = threadIdx.x >> 3;
    int stg  = threadIdx.x & 7;

    for (int fc = 0; fc < FHALF / FC; ++fc) {
        int f0 = fbase + fc * FC;
        floatx4 hacc[4][2];
        #pragma unroll
        for (int mt = 0; mt < 4; ++mt) { hacc[mt][0] = (floatx4){0.f,0.f,0.f,0.f};
                                         hacc[mt][1] = (floatx4){0.f,0.f,0.f,0.f}; }
        for (int kc = 0; kc < D_DIM / KC; ++kc) {
            int k0 = kc * KC;
            {
                const float* xr = x + (size_t)tks[srow] * D_DIM + k0;
                #pragma unroll
                for (int j = 0; j < 8; ++j) {
                    int c = (stg + j * 8) * 4;
                    float4 v = *(const float4*)(xr + c);
                    half4_t hv = { (_Float16)v.x, (_Float16)v.y,
                                   (_Float16)v.z, (_Float16)v.w };
                    *(half4_t*)&Xs[srow][c] = hv;
                }
            }
            __syncthreads();
            #pragma unroll
            for (int ks = 0; ks < KC / 32; ++ks) {
                int kk = ks * 32 + quad * 8;
                half8_t a[4];
                #pragma unroll
                for (int mt = 0; mt < 4; ++mt)
                    a[mt] = *(const half8_t*)&Xs[mt * 16 + ln][kk];
                #pragma unroll
                for (int nt = 0; nt < 2; ++nt) {
                    int fcol = f0 + w * 32 + nt * 16 + ln;
                    const float* wp = W1e + (size_t)(k0 + kk) * F_DIM + fcol;
                    half8_t bfr;
                    #pragma unroll
                    for (int j = 0; j < 8; ++j)
                        bfr[j] = (_Float16)wp[(size_t)j * F_DIM];
                    #pragma unroll
                    for (int mt = 0; mt < 4; ++mt)
                        hacc[mt][nt] = __builtin_amdgcn_mfma_f32_16x16x32_f16(
                            a[mt], bfr, hacc[mt][nt], 0, 0, 0);
                }
            }
            __syncthreads();
        }
        #pragma unroll
        for (int nt = 0; nt < 2; ++nt) {
            int fcol_l = w * 32 + nt * 16 + ln;
            float b1v = b1e[f0 + fcol_l];
            #pragma unroll
            for (int mt = 0; mt < 4; ++mt)
                #pragma unroll
                for (int r2 = 0; r2 < 4; ++r2) {
                    float v = hacc[mt][nt][r2] + b1v;
                    float hs = v / (1.f + __expf(-v));
                    Hs[mt * 16 + quad * 4 + r2][fcol_l] = (_Float16)hs;
                }
        }
        __syncthreads();
        #pragma unroll
        for (int ks = 0; ks < FC / 32; ++ks) {
            int kk = ks * 32 + quad * 8;
            half8_t a[4];
            #pragma unroll
            for (int mt = 0; mt < 4; ++mt)
                a[mt] = *(const half8_t*)&Hs[mt * 16 + ln][kk];
            #pragma unroll
            for (int nt = 0; nt < 8; ++nt) {
                int dcol = w * 128 + nt * 16 + ln;
                const float* wp = W2e + (size_t)(f0 + kk) * D_DIM + dcol;
                half8_t bfr;
                #pragma unroll
                for (int j = 0; j < 8; ++j)
                    bfr[j] = (_Float16)wp[(size_t)j * D_DIM];
                #pragma unroll
                for (int mt = 0; mt < 4; ++mt)
                    oacc[mt][nt] = __builtin_amdgcn_mfma_f32_16x16x32_f16(
                        a[mt], bfr, oacc[mt][nt], 0, 0, 0);
            }
        }
        __syncthreads();
    }
    #pragma unroll
    for (int mt = 0; mt < 4; ++mt) {
        #pragma unroll
        for (int r2 = 0; r2 < 4; ++r2) {
            int row = mt * 16 + quad * 4 + r2;
            if (row >= mcnt) continue;
            float* orow = out + (size_t)tks[row] * D_DIM;
            #pragma unroll
            for (int nt = 0; nt < 8; ++nt) {
                int dcol = w * 128 + nt * 16 + ln;
                float v = oacc[mt][nt][r2];
                if (fhalf == 0) v += b2e[dcol];
                atomicAdd(orow + dcol, v);
            }
        }
    }
}

extern "C" void kernel_launch(void* const* d_in, const int* in_sizes, int n_in,
                              void* d_out, int out_size, void* d_ws, size_t ws_size,
                              hipStream_t stream) {
    const float* x  = (const float*)d_in[0];
    const float* Wg = (const float*)d_in[1];
    const float* bg = (const float*)d_in[2];
    const float* W1 = (const float*)d_in[3];
    const float* b1 = (const float*)d_in[4];
    const float* W2 = (const float*)d_in[5];
    const float* b2 = (const float*)d_in[6];
    float* out = (float*)d_out;

    // ws layout: [cnt 16B][pad][lists @512B, 128KB][W1m 32MB][W2m 32MB][xh 16MB]
    const size_t OFF_LISTS = 512;
    const size_t OFF_W1M   = 131584;                       // 512 + 4*8192*4
    const size_t OFF_W2M   = OFF_W1M + (size_t)E_NUM * D_DIM * F_DIM * 2;
    const size_t OFF_XH    = OFF_W2M + (size_t)E_NUM * D_DIM * F_DIM * 2;
    const size_t WS_NEED   = OFF_XH + (size_t)NTOK * D_DIM * 2;

    int* cnt   = (int*)d_ws;
    int* lists = (int*)((char*)d_ws + OFF_LISTS);

    hipMemsetAsync(cnt, 0, 16, stream);
    hipMemsetAsync(d_out, 0, (size_t)out_size * sizeof(float), stream);

    if (ws_size >= WS_NEED) {
        _Float16* W1m = (_Float16*)((char*)d_ws + OFF_W1M);
        _Float16* W2m = (_Float16*)((char*)d_ws + OFF_W2M);
        _Float16* xh  = (_Float16*)((char*)d_ws + OFF_XH);

        // gating + x fp32->fp16 fused, block-aggregated atomics
        gate_kernel<true><<<NTOK / 32, 256, 0, stream>>>(x, Wg, bg, xh, cnt, lists);

        // W1 [E][D(k)][F(n)] -> fragment tiles (NB=F/16, KB=D/32)
        tile_pack_kernel<<<dim3(F_DIM / 32, D_DIM / 32, E_NUM), 256, 0, stream>>>(
            W1, W1m, D_DIM, F_DIM);
        // W2 [E][F(k)][D(n)] -> fragment tiles (NB=D/16, KB=F/32)
        tile_pack_kernel<<<dim3(D_DIM / 32, F_DIM / 32, E_NUM), 256, 0, stream>>>(
            W2, W2m, F_DIM, D_DIM);

        moe_fast_kernel<<<NWORK, 512, 0, stream>>>(xh, W1m, b1, W2m, b2, cnt, lists, out);
    } else {
        gate_kernel<false><<<NTOK / 32, 256, 0, stream>>>(x, Wg, bg, nullptr, cnt, lists);
        moe_slow_kernel<<<520, 512, 0, stream>>>(x, W1, b1, W2, b2, cnt, lists, out);
    }
}

// Round 6
// 672.489 us; speedup vs baseline: 2.2383x; 2.2383x over previous
//
#include <hip/hip_runtime.h>
#include <hip/hip_fp16.h>

#define D_DIM 1024
#define E_NUM 4
#define F_DIM 4096
#define NTOK 8192         // B*S = 4*2048
#define MT 64             // tokens per tile
#define FC 256            // F-chunk width
#define KC 256            // K-chunk for staging
#define FHALF 2048        // F per block (fallback kernels, F split in 2)
#define NWORK 520         // fallback grid: 8 XCDs * 65 slots
#define NWORK_A 4160      // pass A: 16 fc-chunks * <=260 tiles, 8*520
#define NWORK_B 2080      // pass B: 8 (dq,kh) * <=260 tiles, 8*260
#define HROWS_MAX 16640   // sum ceil(cnt_e/64)*64 <= 16384 + 4*63, rounded

typedef _Float16 half8_t __attribute__((ext_vector_type(8)));
typedef _Float16 half4_t __attribute__((ext_vector_type(4)));
typedef float floatx4 __attribute__((ext_vector_type(4)));

// ---------------- gating: top-2 selection, block-aggregated routing lists ------
template<bool WRITE_XH>
__global__ __launch_bounds__(256) void gate_kernel(
    const float* __restrict__ x, const float* __restrict__ Wg,
    const float* __restrict__ bg, _Float16* __restrict__ xh,
    int* __restrict__ cnt, int* __restrict__ lists)
{
    __shared__ int sel[32];
    __shared__ int loc[4][32];
    __shared__ int lbase[4], lnum[4];

    int wave = threadIdx.x >> 6;
    int lane = threadIdx.x & 63;
    int tbase = blockIdx.x * 32;

    for (int i = 0; i < 8; ++i) {
        int slot = wave * 8 + i;
        int tok = tbase + slot;
        const float* xr = x + (size_t)tok * D_DIM;
        double a0 = 0.0, a1 = 0.0, a2 = 0.0, a3 = 0.0;
        #pragma unroll
        for (int it = 0; it < 4; ++it) {
            int i0 = it * 256 + lane * 4;
            float4 xv = *(const float4*)(xr + i0);
            if (WRITE_XH) {
                half4_t hv = { (_Float16)xv.x, (_Float16)xv.y,
                               (_Float16)xv.z, (_Float16)xv.w };
                *(half4_t*)(xh + (size_t)tok * D_DIM + i0) = hv;
            }
            float4 w0 = *(const float4*)(Wg + (size_t)i0 * 4);
            float4 w1 = *(const float4*)(Wg + (size_t)i0 * 4 + 4);
            float4 w2 = *(const float4*)(Wg + (size_t)i0 * 4 + 8);
            float4 w3 = *(const float4*)(Wg + (size_t)i0 * 4 + 12);
            a0 += (double)xv.x * w0.x + (double)xv.y * w1.x
                + (double)xv.z * w2.x + (double)xv.w * w3.x;
            a1 += (double)xv.x * w0.y + (double)xv.y * w1.y
                + (double)xv.z * w2.y + (double)xv.w * w3.y;
            a2 += (double)xv.x * w0.z + (double)xv.y * w1.z
                + (double)xv.z * w2.z + (double)xv.w * w3.z;
            a3 += (double)xv.x * w0.w + (double)xv.y * w1.w
                + (double)xv.z * w2.w + (double)xv.w * w3.w;
        }
        #pragma unroll
        for (int off = 32; off > 0; off >>= 1) {
            a0 += __shfl_down(a0, off);
            a1 += __shfl_down(a1, off);
            a2 += __shfl_down(a2, off);
            a3 += __shfl_down(a3, off);
        }
        if (lane == 0) {
            double lg[4] = { a0 + (double)bg[0], a1 + (double)bg[1],
                             a2 + (double)bg[2], a3 + (double)bg[3] };
            int i1 = 0;
            for (int e = 1; e < 4; ++e) if (lg[e] > lg[i1]) i1 = e;   // first max wins
            int i2 = -1;
            for (int e = 0; e < 4; ++e) {
                if (e == i1) continue;
                if (i2 < 0 || lg[e] > lg[i2]) i2 = e;
            }
            sel[slot] = i1 * 4 + i2;
        }
    }
    __syncthreads();
    if (threadIdx.x < 4) {
        int e = threadIdx.x, n = 0;
        for (int s = 0; s < 32; ++s) {
            int v = sel[s];
            if ((v >> 2) == e || (v & 3) == e) loc[e][n++] = tbase + s;
        }
        lnum[e] = n;
        lbase[e] = atomicAdd(&cnt[e], n);
    }
    __syncthreads();
    {
        int e = threadIdx.x >> 6;
        int j = threadIdx.x & 63;
        if (j < lnum[e]) lists[e * NTOK + lbase[e] + j] = loc[e][j];
    }
}

// ---------------- prep: pack fp32 [z][R(k)][C(n)] into MFMA fragment tiles ----------
__global__ __launch_bounds__(256) void tile_pack_kernel(
    const float* __restrict__ src, _Float16* __restrict__ dst, int R, int C)
{
    __shared__ _Float16 t2[32][36];     // [c_local][r_local]
    int r0 = blockIdx.y * 32, c0 = blockIdx.x * 32;
    const float* s = src + (size_t)blockIdx.z * R * C;
    _Float16* d = dst + (size_t)blockIdx.z * R * C;
    int tx = threadIdx.x & 31, ty = threadIdx.x >> 5;
    #pragma unroll
    for (int i = 0; i < 4; ++i) {
        int r = ty + i * 8;
        t2[tx][r] = (_Float16)s[(size_t)(r0 + r) * C + c0 + tx];
    }
    __syncthreads();
    int KB = R >> 5;
    int idx = threadIdx.x * 4;                 // 4 halves per thread
    int frag_h = idx >> 9;
    int rem = idx & 511;
    int quad = rem >> 7, ln = (rem >> 3) & 15, j0 = rem & 7;
    int cl = frag_h * 16 + ln, rl = quad * 8 + j0;
    half4_t v = { t2[cl][rl], t2[cl][rl + 1], t2[cl][rl + 2], t2[cl][rl + 3] };
    size_t off = ((size_t)(((c0 >> 4) + frag_h) * KB + (r0 >> 5))) * 512 + rem;
    *(half4_t*)&d[off] = v;
}

// ---- shared decode: (r in [0,T)) -> expert/tile/padded-tile prefix ----
__device__ __forceinline__ void decode_tile(
    int r, int nb0, int nb1, int nb2,
    int& expert, int& tile, int& hbase)
{
    if (r < nb0)                  { expert = 0; tile = r;                 hbase = 0; }
    else if (r < nb0 + nb1)       { expert = 1; tile = r - nb0;           hbase = nb0; }
    else if (r < nb0 + nb1 + nb2) { expert = 2; tile = r - nb0 - nb1;     hbase = nb0 + nb1; }
    else                          { expert = 3; tile = r - nb0 - nb1 - nb2; hbase = nb0 + nb1 + nb2; }
}

// ---------------- pass A: H = swish(X @ W1 + b1), fp16 -> ws ----------------
// Item = (tile 64 tok, fc 256 f-cols). hacc[4][2]=32 regs -> 4 waves/SIMD,
// 2 blocks/CU (vs 2 waves/SIMD in the fused kernel). GEMM1 inner loop is
// verbatim from the verified 726us kernel. XCD remap fc-major: the 520 works
// on one XCD share a ~512KB W1 slice through its L2; xh (16MB) is L3-resident.
__global__ __launch_bounds__(512, 4) void h1_kernel(
    const _Float16* __restrict__ xh, const _Float16* __restrict__ W1m,
    const float* __restrict__ b1, const int* __restrict__ cnt,
    const int* __restrict__ lists, _Float16* __restrict__ Hbuf)
{
    __shared__ _Float16 Xs[MT][KC + 8];
    __shared__ _Float16 Hsd[MT][FC + 8];
    __shared__ int tks[MT];

    int b = blockIdx.x;
    int work = (b & 7) * (NWORK_A / 8) + (b >> 3);

    int nb0 = (cnt[0] + MT - 1) / MT;
    int nb1 = (cnt[1] + MT - 1) / MT;
    int nb2 = (cnt[2] + MT - 1) / MT;
    int nb3 = (cnt[3] + MT - 1) / MT;
    int T = nb0 + nb1 + nb2 + nb3;
    if (work >= 16 * T) return;

    int fc = work / T;
    int r  = work % T;
    int expert, tile, hbase;
    decode_tile(r, nb0, nb1, nb2, expert, tile, hbase);
    int mcnt = min(MT, cnt[expert] - tile * MT);

    if (threadIdx.x < MT) {
        int idx = tile * MT + (int)threadIdx.x;
        tks[threadIdx.x] = lists[expert * NTOK + ((int)threadIdx.x < mcnt ? idx : tile * MT)];
    }
    __syncthreads();

    const half8_t* W1f = (const half8_t*)(W1m + (size_t)expert * D_DIM * F_DIM);
    const float* b1e = b1 + (size_t)expert * F_DIM;

    int w = threadIdx.x >> 6;
    int lane = threadIdx.x & 63;
    int quad = lane >> 4;
    int ln = lane & 15;
    int srow = threadIdx.x >> 3;
    int stg  = threadIdx.x & 7;

    int f0 = fc * FC;
    int fb0 = (f0 >> 4) + w * 2;

    floatx4 hacc[4][2];
    #pragma unroll
    for (int mt = 0; mt < 4; ++mt) { hacc[mt][0] = (floatx4){0.f,0.f,0.f,0.f};
                                     hacc[mt][1] = (floatx4){0.f,0.f,0.f,0.f}; }

    for (int kc = 0; kc < D_DIM / KC; ++kc) {
        int k0 = kc * KC;
        {
            const _Float16* xr = xh + (size_t)tks[srow] * D_DIM + k0 + stg * 32;
            half8_t v0 = *(const half8_t*)(xr);
            half8_t v1 = *(const half8_t*)(xr + 8);
            half8_t v2 = *(const half8_t*)(xr + 16);
            half8_t v3 = *(const half8_t*)(xr + 24);
            *(half8_t*)&Xs[srow][stg * 32]      = v0;
            *(half8_t*)&Xs[srow][stg * 32 + 8]  = v1;
            *(half8_t*)&Xs[srow][stg * 32 + 16] = v2;
            *(half8_t*)&Xs[srow][stg * 32 + 24] = v3;
        }
        __syncthreads();

        #pragma unroll
        for (int ks = 0; ks < KC / 32; ++ks) {
            int kk = ks * 32 + quad * 8;
            int kb = kc * 8 + ks;
            half8_t a[4];
            #pragma unroll
            for (int mt = 0; mt < 4; ++mt)
                a[mt] = *(const half8_t*)&Xs[mt * 16 + ln][kk];
            #pragma unroll
            for (int nt = 0; nt < 2; ++nt) {
                half8_t bfr = W1f[((size_t)((fb0 + nt) * 32 + kb)) * 64 + lane];
                #pragma unroll
                for (int mt = 0; mt < 4; ++mt)
                    hacc[mt][nt] = __builtin_amdgcn_mfma_f32_16x16x32_f16(
                        a[mt], bfr, hacc[mt][nt], 0, 0, 0);
            }
        }
        __syncthreads();
    }

    // bias + swish -> Hsd (verbatim index mapping)
    #pragma unroll
    for (int nt = 0; nt < 2; ++nt) {
        int fcol_l = w * 32 + nt * 16 + ln;
        float b1v = b1e[f0 + fcol_l];
        #pragma unroll
        for (int mt = 0; mt < 4; ++mt)
            #pragma unroll
            for (int r2 = 0; r2 < 4; ++r2) {
                float v = hacc[mt][nt][r2] + b1v;
                float hs = v / (1.f + __expf(-v));
                Hsd[mt * 16 + quad * 4 + r2][fcol_l] = (_Float16)hs;
            }
    }
    __syncthreads();

    // coalesced dump Hsd -> Hbuf[(hbase+tile)*64 + srow][f0 + ...]
    {
        size_t hrow0 = ((size_t)(hbase + tile)) * MT;
        _Float16* hdst = Hbuf + (hrow0 + srow) * F_DIM + f0 + stg * 32;
        const _Float16* hsrc = &Hsd[srow][stg * 32];
        half8_t v0 = *(const half8_t*)(hsrc);
        half8_t v1 = *(const half8_t*)(hsrc + 8);
        half8_t v2 = *(const half8_t*)(hsrc + 16);
        half8_t v3 = *(const half8_t*)(hsrc + 24);
        *(half8_t*)(hdst)      = v0;
        *(half8_t*)(hdst + 8)  = v1;
        *(half8_t*)(hdst + 16) = v2;
        *(half8_t*)(hdst + 24) = v3;
    }
}

// ---------------- pass B: out += H @ W2 (+ b2 once) ----------------
// Item = (tile 64 tok, dq: 256 d-cols, kh: half of F). oacc[4][2]=32 regs ->
// 4 waves/SIMD, 2 blocks/CU. d-split is atomic-neutral (exclusive d-ranges);
// k-split accumulates through the existing atomics; bias only when kh==0.
// XCD remap (dq,kh)-major: one XCD's 260 works share a 1MB W2 slice via L2.
__global__ __launch_bounds__(512, 4) void o2_kernel(
    const _Float16* __restrict__ Hbuf, const _Float16* __restrict__ W2m,
    const float* __restrict__ b2, const int* __restrict__ cnt,
    const int* __restrict__ lists, float* __restrict__ out)
{
    __shared__ _Float16 Hs[MT][KC + 8];
    __shared__ int tks[MT];

    int b = blockIdx.x;
    int work = (b & 7) * (NWORK_B / 8) + (b >> 3);

    int nb0 = (cnt[0] + MT - 1) / MT;
    int nb1 = (cnt[1] + MT - 1) / MT;
    int nb2 = (cnt[2] + MT - 1) / MT;
    int nb3 = (cnt[3] + MT - 1) / MT;
    int T = nb0 + nb1 + nb2 + nb3;
    if (work >= 8 * T) return;

    int s = work / T;                 // 0..7
    int r = work % T;
    int dq = s >> 1;                  // d-quarter 0..3
    int kh = s & 1;                   // k-half 0..1
    int expert, tile, hbase;
    decode_tile(r, nb0, nb1, nb2, expert, tile, hbase);
    int mcnt = min(MT, cnt[expert] - tile * MT);

    if (threadIdx.x < MT) {
        int idx = tile * MT + (int)threadIdx.x;
        tks[threadIdx.x] = lists[expert * NTOK + ((int)threadIdx.x < mcnt ? idx : tile * MT)];
    }
    __syncthreads();

    const half8_t* W2f = (const half8_t*)(W2m + (size_t)expert * D_DIM * F_DIM);
    const float* b2e = b2 + (size_t)expert * D_DIM;

    int w = threadIdx.x >> 6;
    int lane = threadIdx.x & 63;
    int quad = lane >> 4;
    int ln = lane & 15;
    int srow = threadIdx.x >> 3;
    int stg  = threadIdx.x & 7;

    size_t hrow0 = ((size_t)(hbase + tile)) * MT;
    const _Float16* hrow = Hbuf + (hrow0 + srow) * F_DIM + stg * 32;

    floatx4 oacc[4][2];
    #pragma unroll
    for (int mt = 0; mt < 4; ++mt) { oacc[mt][0] = (floatx4){0.f,0.f,0.f,0.f};
                                     oacc[mt][1] = (floatx4){0.f,0.f,0.f,0.f}; }

    for (int kc = kh * 8; kc < kh * 8 + 8; ++kc) {
        {
            const _Float16* hr = hrow + kc * KC;
            half8_t v0 = *(const half8_t*)(hr);
            half8_t v1 = *(const half8_t*)(hr + 8);
            half8_t v2 = *(const half8_t*)(hr + 16);
            half8_t v3 = *(const half8_t*)(hr + 24);
            *(half8_t*)&Hs[srow][stg * 32]      = v0;
            *(half8_t*)&Hs[srow][stg * 32 + 8]  = v1;
            *(half8_t*)&Hs[srow][stg * 32 + 16] = v2;
            *(half8_t*)&Hs[srow][stg * 32 + 24] = v3;
        }
        __syncthreads();

        #pragma unroll
        for (int ks = 0; ks < KC / 32; ++ks) {
            int kk = ks * 32 + quad * 8;
            int fkb = kc * 8 + ks;
            half8_t a[4];
            #pragma unroll
            for (int mt = 0; mt < 4; ++mt)
                a[mt] = *(const half8_t*)&Hs[mt * 16 + ln][kk];
            #pragma unroll
            for (int nt = 0; nt < 2; ++nt) {
                int db = dq * 16 + w * 2 + nt;     // d-frag 0..63
                half8_t bfr = W2f[((size_t)(db * 128 + fkb)) * 64 + lane];
                #pragma unroll
                for (int mt = 0; mt < 4; ++mt)
                    oacc[mt][nt] = __builtin_amdgcn_mfma_f32_16x16x32_f16(
                        a[mt], bfr, oacc[mt][nt], 0, 0, 0);
            }
        }
        __syncthreads();
    }

    // epilogue: exclusive d-range per item; bias once (kh==0)
    #pragma unroll
    for (int mt = 0; mt < 4; ++mt) {
        #pragma unroll
        for (int r2 = 0; r2 < 4; ++r2) {
            int row = mt * 16 + quad * 4 + r2;
            if (row >= mcnt) continue;
            float* orow = out + (size_t)tks[row] * D_DIM;
            #pragma unroll
            for (int nt = 0; nt < 2; ++nt) {
                int dcol = dq * 256 + w * 32 + nt * 16 + ln;
                float v = oacc[mt][nt][r2];
                if (kh == 0) v += b2e[dcol];
                atomicAdd(orow + dcol, v);
            }
        }
    }
}

// ---------------- fallback: fused fast kernel (verified 726us, round-4) -------
__global__ __launch_bounds__(512, 2) void moe_fast_kernel(
    const _Float16* __restrict__ xh, const _Float16* __restrict__ W1m,
    const float* __restrict__ b1, const _Float16* __restrict__ W2m,
    const float* __restrict__ b2, const int* __restrict__ cnt,
    const int* __restrict__ lists, float* __restrict__ out)
{
    __shared__ _Float16 Xs[MT][KC + 8];
    __shared__ _Float16 Hsd[MT][FC + 8];
    __shared__ int tks[MT];

    int b = blockIdx.x;
    int work = (b & 7) * (NWORK / 8) + (b >> 3);

    int nb0 = (cnt[0] + MT - 1) / MT;
    int nb1 = (cnt[1] + MT - 1) / MT;
    int nb2 = (cnt[2] + MT - 1) / MT;
    int nb3 = (cnt[3] + MT - 1) / MT;
    int T = nb0 + nb1 + nb2 + nb3;

    int fhalf, r;
    if (work < T) { fhalf = 0; r = work; }
    else if (work < 2 * T) { fhalf = 1; r = work - T; }
    else return;

    int expert, tile, hbase;
    decode_tile(r, nb0, nb1, nb2, expert, tile, hbase);
    int mcnt = min(MT, cnt[expert] - tile * MT);

    if (threadIdx.x < MT) {
        int idx = tile * MT + (int)threadIdx.x;
        tks[threadIdx.x] = lists[expert * NTOK + ((int)threadIdx.x < mcnt ? idx : tile * MT)];
    }
    __syncthreads();

    const half8_t* W1f = (const half8_t*)(W1m + (size_t)expert * D_DIM * F_DIM);
    const half8_t* W2f = (const half8_t*)(W2m + (size_t)expert * D_DIM * F_DIM);
    const float* b1e = b1 + (size_t)expert * F_DIM;
    const float* b2e = b2 + (size_t)expert * D_DIM;

    int w = threadIdx.x >> 6;
    int lane = threadIdx.x & 63;
    int quad = lane >> 4;
    int ln = lane & 15;

    floatx4 oacc[4][8];
    #pragma unroll
    for (int mt = 0; mt < 4; ++mt)
        #pragma unroll
        for (int nt = 0; nt < 8; ++nt)
            oacc[mt][nt] = (floatx4){0.f, 0.f, 0.f, 0.f};

    int fbase = fhalf * FHALF;
    int srow = threadIdx.x >> 3;
    int stg  = threadIdx.x & 7;

    for (int fc = 0; fc < FHALF / FC; ++fc) {
        int f0 = fbase + fc * FC;
        int fb0 = (f0 >> 4) + w * 2;

        floatx4 hacc[4][2];
        #pragma unroll
        for (int mt = 0; mt < 4; ++mt) { hacc[mt][0] = (floatx4){0.f,0.f,0.f,0.f};
                                         hacc[mt][1] = (floatx4){0.f,0.f,0.f,0.f}; }

        for (int kc = 0; kc < D_DIM / KC; ++kc) {
            int k0 = kc * KC;
            {
                const _Float16* xr = xh + (size_t)tks[srow] * D_DIM + k0 + stg * 32;
                half8_t v0 = *(const half8_t*)(xr);
                half8_t v1 = *(const half8_t*)(xr + 8);
                half8_t v2 = *(const half8_t*)(xr + 16);
                half8_t v3 = *(const half8_t*)(xr + 24);
                *(half8_t*)&Xs[srow][stg * 32]      = v0;
                *(half8_t*)&Xs[srow][stg * 32 + 8]  = v1;
                *(half8_t*)&Xs[srow][stg * 32 + 16] = v2;
                *(half8_t*)&Xs[srow][stg * 32 + 24] = v3;
            }
            __syncthreads();

            #pragma unroll
            for (int ks = 0; ks < KC / 32; ++ks) {
                int kk = ks * 32 + quad * 8;
                int kb = kc * 8 + ks;
                half8_t a[4];
                #pragma unroll
                for (int mt = 0; mt < 4; ++mt)
                    a[mt] = *(const half8_t*)&Xs[mt * 16 + ln][kk];
                #pragma unroll
                for (int nt = 0; nt < 2; ++nt) {
                    half8_t bfr = W1f[((size_t)((fb0 + nt) * 32 + kb)) * 64 + lane];
                    #pragma unroll
                    for (int mt = 0; mt < 4; ++mt)
                        hacc[mt][nt] = __builtin_amdgcn_mfma_f32_16x16x32_f16(
                            a[mt], bfr, hacc[mt][nt], 0, 0, 0);
                }
            }
            __syncthreads();
        }

        #pragma unroll
        for (int nt = 0; nt < 2; ++nt) {
            int fcol_l = w * 32 + nt * 16 + ln;
            float b1v = b1e[f0 + fcol_l];
            #pragma unroll
            for (int mt = 0; mt < 4; ++mt)
                #pragma unroll
                for (int r2 = 0; r2 < 4; ++r2) {
                    float v = hacc[mt][nt][r2] + b1v;
                    float hs = v / (1.f + __expf(-v));
                    Hsd[mt * 16 + quad * 4 + r2][fcol_l] = (_Float16)hs;
                }
        }
        __syncthreads();

        #pragma unroll
        for (int ks = 0; ks < FC / 32; ++ks) {
            int kk = ks * 32 + quad * 8;
            int fkb = (f0 >> 5) + ks;
            half8_t a[4];
            #pragma unroll
            for (int mt = 0; mt < 4; ++mt)
                a[mt] = *(const half8_t*)&Hsd[mt * 16 + ln][kk];
            #pragma unroll
            for (int nt = 0; nt < 8; ++nt) {
                int db = w * 8 + nt;
                half8_t bfr = W2f[((size_t)(db * 128 + fkb)) * 64 + lane];
                #pragma unroll
                for (int mt = 0; mt < 4; ++mt)
                    oacc[mt][nt] = __builtin_amdgcn_mfma_f32_16x16x32_f16(
                        a[mt], bfr, oacc[mt][nt], 0, 0, 0);
            }
        }
        __syncthreads();
    }

    #pragma unroll
    for (int mt = 0; mt < 4; ++mt) {
        #pragma unroll
        for (int r2 = 0; r2 < 4; ++r2) {
            int row = mt * 16 + quad * 4 + r2;
            if (row >= mcnt) continue;
            float* orow = out + (size_t)tks[row] * D_DIM;
            #pragma unroll
            for (int nt = 0; nt < 8; ++nt) {
                int dcol = w * 128 + nt * 16 + ln;
                float v = oacc[mt][nt][r2];
                if (fhalf == 0) v += b2e[dcol];
                atomicAdd(orow + dcol, v);
            }
        }
    }
}

// ---------------- fallback kernel: fp32 weights on the fly (ws too small) ----------
__global__ __launch_bounds__(512, 2) void moe_slow_kernel(
    const float* __restrict__ x, const float* __restrict__ W1,
    const float* __restrict__ b1, const float* __restrict__ W2,
    const float* __restrict__ b2, const int* __restrict__ cnt,
    const int* __restrict__ lists, float* __restrict__ out)
{
    __shared__ _Float16 Xs[MT][KC + 8];
    __shared__ _Float16 Hsd[MT][FC + 8];
    __shared__ int tks[MT];

    int fhalf = blockIdx.x & 1;
    int bi = blockIdx.x >> 1;
    int expert = -1, tile = 0, mcnt = 0;
    int rem = bi;
    for (int e = 0; e < E_NUM; ++e) {
        int n = cnt[e];
        int nbt = (n + MT - 1) / MT;
        if (rem < nbt) { expert = e; tile = rem; mcnt = min(MT, n - rem * MT); break; }
        rem -= nbt;
    }
    if (expert < 0) return;

    if (threadIdx.x < MT) {
        int idx = tile * MT + (int)threadIdx.x;
        tks[threadIdx.x] = lists[expert * NTOK + ((int)threadIdx.x < mcnt ? idx : tile * MT)];
    }
    __syncthreads();

    const float* W1e = W1 + (size_t)expert * D_DIM * F_DIM;
    const float* W2e = W2 + (size_t)expert * F_DIM * D_DIM;
    const float* b1e = b1 + (size_t)expert * F_DIM;
    const float* b2e = b2 + (size_t)expert * D_DIM;

    int w = threadIdx.x >> 6;
    int lane = threadIdx.x & 63;
    int quad = lane >> 4;
    int ln = lane & 15;

    floatx4 oacc[4][8];
    #pragma unroll
    for (int mt = 0; mt < 4; ++mt)
        #pragma unroll
        for (int nt = 0; nt < 8; ++nt)
            oacc[mt][nt] = (floatx4){0.f, 0.f, 0.f, 0.f};

    int fbase = fhalf * FHALF;
    int srow = threadIdx.x >> 3;
    int stg  = threadIdx.x & 7;

    for (int fc = 0; fc < FHALF / FC; ++fc) {
        int f0 = fbase + fc * FC;
        floatx4 hacc[4][2];
        #pragma unroll
        for (int mt = 0; mt < 4; ++mt) { hacc[mt][0] = (floatx4){0.f,0.f,0.f,0.f};
                                         hacc[mt][1] = (floatx4){0.f,0.f,0.f,0.f}; }
        for (int kc = 0; kc < D_DIM / KC; ++kc) {
            int k0 = kc * KC;
            {
                const float* xr = x + (size_t)tks[srow] * D_DIM + k0;
                #pragma unroll
                for (int j = 0; j < 8; ++j) {
                    int c = (stg + j * 8) * 4;
                    float4 v = *(const float4*)(xr + c);
                    half4_t hv = { (_Float16)v.x, (_Float16)v.y,
                                   (_Float16)v.z, (_Float16)v.w };
                    *(half4_t*)&Xs[srow][c] = hv;
                }
            }
            __syncthreads();
            #pragma unroll
            for (int ks = 0; ks < KC / 32; ++ks) {
                int kk = ks * 32 + quad * 8;
                half8_t a[4];
                #pragma unroll
                for (int mt = 0; mt < 4; ++mt)
                    a[mt] = *(const half8_t*)&Xs[mt * 16 + ln][kk];
                #pragma unroll
                for (int nt = 0; nt < 2; ++nt) {
                    int fcol = f0 + w * 32 + nt * 16 + ln;
                    const float* wp = W1e + (size_t)(k0 + kk) * F_DIM + fcol;
                    half8_t bfr;
                    #pragma unroll
                    for (int j = 0; j < 8; ++j)
                        bfr[j] = (_Float16)wp[(size_t)j * F_DIM];
                    #pragma unroll
                    for (int mt = 0; mt < 4; ++mt)
                        hacc[mt][nt] = __builtin_amdgcn_mfma_f32_16x16x32_f16(
                            a[mt], bfr, hacc[mt][nt], 0, 0, 0);
                }
            }
            __syncthreads();
        }
        #pragma unroll
        for (int nt = 0; nt < 2; ++nt) {
            int fcol_l = w * 32 + nt * 16 + ln;
            float b1v = b1e[f0 + fcol_l];
            #pragma unroll
            for (int mt = 0; mt < 4; ++mt)
                #pragma unroll
                for (int r2 = 0; r2 < 4; ++r2) {
                    float v = hacc[mt][nt][r2] + b1v;
                    float hs = v / (1.f + __expf(-v));
                    Hsd[mt * 16 + quad * 4 + r2][fcol_l] = (_Float16)hs;
                }
        }
        __syncthreads();
        #pragma unroll
        for (int ks = 0; ks < FC / 32; ++ks) {
            int kk = ks * 32 + quad * 8;
            half8_t a[4];
            #pragma unroll
            for (int mt = 0; mt < 4; ++mt)
                a[mt] = *(const half8_t*)&Hsd[mt * 16 + ln][kk];
            #pragma unroll
            for (int nt = 0; nt < 8; ++nt) {
                int dcol = w * 128 + nt * 16 + ln;
                const float* wp = W2e + (size_t)(f0 + kk) * D_DIM + dcol;
                half8_t bfr;
                #pragma unroll
                for (int j = 0; j < 8; ++j)
                    bfr[j] = (_Float16)wp[(size_t)j * D_DIM];
                #pragma unroll
                for (int mt = 0; mt < 4; ++mt)
                    oacc[mt][nt] = __builtin_amdgcn_mfma_f32_16x16x32_f16(
                        a[mt], bfr, oacc[mt][nt], 0, 0, 0);
            }
        }
        __syncthreads();
    }
    #pragma unroll
    for (int mt = 0; mt < 4; ++mt) {
        #pragma unroll
        for (int r2 = 0; r2 < 4; ++r2) {
            int row = mt * 16 + quad * 4 + r2;
            if (row >= mcnt) continue;
            float* orow = out + (size_t)tks[row] * D_DIM;
            #pragma unroll
            for (int nt = 0; nt < 8; ++nt) {
                int dcol = w * 128 + nt * 16 + ln;
                float v = oacc[mt][nt][r2];
                if (fhalf == 0) v += b2e[dcol];
                atomicAdd(orow + dcol, v);
            }
        }
    }
}

extern "C" void kernel_launch(void* const* d_in, const int* in_sizes, int n_in,
                              void* d_out, int out_size, void* d_ws, size_t ws_size,
                              hipStream_t stream) {
    const float* x  = (const float*)d_in[0];
    const float* Wg = (const float*)d_in[1];
    const float* bg = (const float*)d_in[2];
    const float* W1 = (const float*)d_in[3];
    const float* b1 = (const float*)d_in[4];
    const float* W2 = (const float*)d_in[5];
    const float* b2 = (const float*)d_in[6];
    float* out = (float*)d_out;

    // ws layout: [cnt 16B][pad][lists @512B][W1m 32MB][W2m 32MB][xh 16MB][H 136MB]
    const size_t OFF_LISTS = 512;
    const size_t OFF_W1M   = 131584;                       // 512 + 4*8192*4
    const size_t OFF_W2M   = OFF_W1M + (size_t)E_NUM * D_DIM * F_DIM * 2;
    const size_t OFF_XH    = OFF_W2M + (size_t)E_NUM * D_DIM * F_DIM * 2;
    const size_t OFF_H     = OFF_XH + (size_t)NTOK * D_DIM * 2;
    const size_t WS_NEED   = OFF_H;                               // fused path
    const size_t WS_NEED2  = OFF_H + (size_t)HROWS_MAX * F_DIM * 2;   // two-pass

    int* cnt   = (int*)d_ws;
    int* lists = (int*)((char*)d_ws + OFF_LISTS);

    hipMemsetAsync(cnt, 0, 16, stream);
    hipMemsetAsync(d_out, 0, (size_t)out_size * sizeof(float), stream);

    if (ws_size >= WS_NEED) {
        _Float16* W1m = (_Float16*)((char*)d_ws + OFF_W1M);
        _Float16* W2m = (_Float16*)((char*)d_ws + OFF_W2M);
        _Float16* xh  = (_Float16*)((char*)d_ws + OFF_XH);

        gate_kernel<true><<<NTOK / 32, 256, 0, stream>>>(x, Wg, bg, xh, cnt, lists);

        tile_pack_kernel<<<dim3(F_DIM / 32, D_DIM / 32, E_NUM), 256, 0, stream>>>(
            W1, W1m, D_DIM, F_DIM);
        tile_pack_kernel<<<dim3(D_DIM / 32, F_DIM / 32, E_NUM), 256, 0, stream>>>(
            W2, W2m, F_DIM, D_DIM);

        if (ws_size >= WS_NEED2) {
            _Float16* Hbuf = (_Float16*)((char*)d_ws + OFF_H);
            h1_kernel<<<NWORK_A, 512, 0, stream>>>(xh, W1m, b1, cnt, lists, Hbuf);
            o2_kernel<<<NWORK_B, 512, 0, stream>>>(Hbuf, W2m, b2, cnt, lists, out);
        } else {
            moe_fast_kernel<<<NWORK, 512, 0, stream>>>(xh, W1m, b1, W2m, b2, cnt, lists, out);
        }
    } else {
        gate_kernel<false><<<NTOK / 32, 256, 0, stream>>>(x, Wg, bg, nullptr, cnt, lists);
        moe_slow_kernel<<<520, 512, 0, stream>>>(x, W1, b1, W2, b2, cnt, lists, out);
    }
}